// Round 5
// baseline (201.384 us; speedup 1.0000x reference)
//
#include <hip/hip_runtime.h>

#define IN_DIM   1024
#define OUT_DIM  1024
#define BATCH    16384

#define BM 128
#define BN 256
#define BK 32

typedef __attribute__((ext_vector_type(8))) short          bf16x8;
typedef __attribute__((ext_vector_type(8))) unsigned short u16x8;
typedef __attribute__((ext_vector_type(4))) unsigned short u16x4;
typedef __attribute__((ext_vector_type(4))) float          f32x4;

__device__ __forceinline__ unsigned short f2bf(float f) {
    unsigned u = __float_as_uint(f);
    u += 0x7FFFu + ((u >> 16) & 1u);          // round-to-nearest-even
    return (unsigned short)(u >> 16);
}
__device__ __forceinline__ float bf2f(unsigned short h) {
    return __uint_as_float((unsigned)h << 16);
}

#define GLOAD_LDS16(g, l)                                                      \
    __builtin_amdgcn_global_load_lds(                                          \
        (const __attribute__((address_space(1))) unsigned int*)(g),            \
        (__attribute__((address_space(3))) unsigned int*)(l), 16, 0, 0)

// barrier with lgkm-only drain: W prefetch (vmcnt) stays in flight (T3/T4)
#define LGKM_BARRIER()                                                         \
    do {                                                                       \
        asm volatile("s_waitcnt lgkmcnt(0)" ::: "memory");                     \
        __builtin_amdgcn_sched_barrier(0);                                     \
        __builtin_amdgcn_s_barrier();                                          \
        __builtin_amdgcn_sched_barrier(0);                                     \
    } while (0)

// ---------------------------------------------------------------------------
// Kernel 1: weight normalization -> split bf16 planes (wh + wl) + log-jac.
// ---------------------------------------------------------------------------
__global__ __launch_bounds__(256) void prep_kernel(
    const float* __restrict__ W, const float* __restrict__ wls,
    unsigned short* __restrict__ wh, unsigned short* __restrict__ wl,
    float* __restrict__ jac)
{
    const int warp = threadIdx.x >> 6;
    const int lane = threadIdx.x & 63;
    const int row  = blockIdx.x * 4 + warp;
    const int r    = row >> 3;
    const int d0   = r * 8;
    const int nk   = d0 + 8;
    const float* Wr = W + (size_t)row * IN_DIM;

    float ss = 0.f;
    for (int k = lane * 4; k < nk; k += 256) {
        float4 v = *(const float4*)&Wr[k];
        if (k >= d0) { v.x = expf(v.x); v.y = expf(v.y); v.z = expf(v.z); v.w = expf(v.w); }
        ss += v.x * v.x + v.y * v.y + v.z * v.z + v.w * v.w;
    }
    #pragma unroll
    for (int off = 32; off >= 1; off >>= 1) ss += __shfl_xor(ss, off);

    const float lscale = wls[row] - 0.5f * logf(ss);
    const float scale  = expf(lscale);

    for (int k = lane * 4; k < IN_DIM; k += 256) {
        float4 v = {0.f, 0.f, 0.f, 0.f};
        if (k < nk) {
            v = *(const float4*)&Wr[k];
            if (k >= d0) { v.x = expf(v.x); v.y = expf(v.y); v.z = expf(v.z); v.w = expf(v.w); }
            v.x *= scale; v.y *= scale; v.z *= scale; v.w *= scale;
        }
        u16x4 h, l;
        const float f[4] = {v.x, v.y, v.z, v.w};
        #pragma unroll
        for (int i = 0; i < 4; ++i) {
            h[i] = f2bf(f[i]);
            l[i] = f2bf(f[i] - bf2f(h[i]));
        }
        *(u16x4*)&wh[(size_t)row * IN_DIM + k] = h;
        *(u16x4*)&wl[(size_t)row * IN_DIM + k] = l;
    }
    if (lane < 8) jac[r * 64 + (row & 7) * 8 + lane] = lscale + Wr[d0 + lane];
}

// ---------------------------------------------------------------------------
// Kernel 2: y = x @ Wn^T + bias, bf16x2-split MFMA (hh + hl + lh).
// 128x256 tile, BK=32, 512 thr / 8 waves (2x4, 64x64 per wave).
// LDS layout is FRAGMENT-ORDERED: [row-block of 16][kslot 0..3][row 0..15][8 bf16]
// so every frag ds_read_b128 / staging write / gload_lds dest is lane-linear
// over a contiguous 1KB block -> zero bank conflicts (rule #21 pattern).
// W: 3 buffers, prefetched 2 K-steps ahead via global_load_lds; barriers drain
// lgkm only (counted-vmcnt discipline: CVT's x-reg wait vmcnt(4) retires
// W(i+1) while W(i+2) stays in flight). x: 2 buffers, reg-staged + fused
// fp32->bf16hi/lo conversion.
// ---------------------------------------------------------------------------
__global__ __launch_bounds__(512, 2) void gemm_kernel(
    const float* __restrict__ x,
    const unsigned short* __restrict__ wh, const unsigned short* __restrict__ wl,
    const float* __restrict__ bias, float* __restrict__ y)
{
    __shared__ __align__(16) unsigned short smem[65536];   // 128 KB
    // x region: [2 buf][2 plane][4096]  (elems 0..16383)
    // W region: [3 buf][2 plane][8192]  (elems 16384..65535)

    const int bid = (int)blockIdx.x;
    const int seg = bid >> 7;                  // 0..3, heaviest first
    const int sb  = bid & 127;
    const int nt  = 3 - seg;
    const int mt  = (sb & 7) * 16 + (sb >> 3); // XCD-affine
    const int m0  = mt * BM;
    const int n0  = nt * BN;
    const int nsteps = (n0 + BN) >> 5;         // Klim / 32, in {8,16,24,32}

    const int t    = threadIdx.x;
    const int lane = t & 63;
    const int wid  = t >> 6;
    const int wr   = wid >> 2;                 // 0..1
    const int wc   = wid & 3;                  // 0..3
    const int lr   = lane & 15;                // frag row in 16-block
    const int lq   = lane >> 4;                // k-slot 0..3

    // x source: thread t owns slot t (row wid*16+lr, kslot lq) -> 8 floats
    const float* xg = x + (size_t)(m0 + wid * 16 + lr) * IN_DIM + lq * 8;

    // W source: wave wid stages row-blocks {2*wid, 2*wid+1} per plane
    const size_t wsrc = (size_t)(n0 + wid * 32 + lr) * IN_DIM + lq * 8;
    const unsigned short* whg = wh + wsrc;
    const unsigned short* wlg = wl + wsrc;

    unsigned short* const xs  = smem;          // x region
    unsigned short* const wsm = smem + 16384;  // W region

    f32x4 acc[4][4];
    #pragma unroll
    for (int i = 0; i < 4; ++i)
        #pragma unroll
        for (int j = 0; j < 4; ++j) acc[i][j] = (f32x4){0.f, 0.f, 0.f, 0.f};

    float4 xva, xvb;

    auto LOAD_X = [&](int k0) {
        xva = *(const float4*)(xg + k0);
        xvb = *(const float4*)(xg + k0 + 4);
    };
    auto STAGE_W = [&](int b, int k0) {        // 4 gload_lds, lane-linear dests
        unsigned short* dh = wsm + b * 16384 + wid * 1024;
        unsigned short* dl = dh + 8192;
        GLOAD_LDS16(whg + k0,                dh);
        GLOAD_LDS16(whg + k0 + 16 * IN_DIM,  dh + 512);
        GLOAD_LDS16(wlg + k0,                dl);
        GLOAD_LDS16(wlg + k0 + 16 * IN_DIM,  dl + 512);
    };
    auto CVT_X = [&](int b) {                  // write slot = t*8 elems (linear!)
        unsigned short* dh = xs + b * 8192;
        const float f[8] = {xva.x, xva.y, xva.z, xva.w, xvb.x, xvb.y, xvb.z, xvb.w};
        u16x8 h, l;
        #pragma unroll
        for (int i = 0; i < 8; ++i) {
            h[i] = f2bf(f[i]);
            l[i] = f2bf(f[i] - bf2f(h[i]));
        }
        *(u16x8*)&dh[t * 8]        = h;
        *(u16x8*)&dh[4096 + t * 8] = l;
    };
    auto COMPUTE = [&](int xb, int wbuf) {
        const unsigned short* xh_ = xs + xb * 8192;
        const unsigned short* xl_ = xh_ + 4096;
        const unsigned short* wh_ = wsm + wbuf * 16384;
        const unsigned short* wl_ = wh_ + 8192;
        const int ao = wr * 2048 + lane * 8;   // frag read: contiguous 1KB/wave
        const int bo = wc * 2048 + lane * 8;
        bf16x8 bh[4], bl[4];
        #pragma unroll
        for (int fc = 0; fc < 4; ++fc) {
            bh[fc] = *(const bf16x8*)&wh_[bo + fc * 512];
            bl[fc] = *(const bf16x8*)&wl_[bo + fc * 512];
        }
        #pragma unroll
        for (int fr = 0; fr < 4; ++fr) {
            const bf16x8 ah = *(const bf16x8*)&xh_[ao + fr * 512];
            const bf16x8 al = *(const bf16x8*)&xl_[ao + fr * 512];
            #pragma unroll
            for (int fc = 0; fc < 4; ++fc) {
                acc[fr][fc] = __builtin_amdgcn_mfma_f32_16x16x32_bf16(ah, bh[fc], acc[fr][fc], 0, 0, 0);
                acc[fr][fc] = __builtin_amdgcn_mfma_f32_16x16x32_bf16(ah, bl[fc], acc[fr][fc], 0, 0, 0);
                acc[fr][fc] = __builtin_amdgcn_mfma_f32_16x16x32_bf16(al, bh[fc], acc[fr][fc], 0, 0, 0);
            }
        }
    };

    // ---- prologue: order matters for the vmcnt retire chain ----
    STAGE_W(0, 0);                 // queue: [W0:4]
    LOAD_X(0);                     //        [W0:4, x:2]
    STAGE_W(1, BK);                //        [W0:4, x:2, W1:4]
    CVT_X(0);                      // x use -> vmcnt(4): retires W0+x, W1 in flight
    LGKM_BARRIER();

    int xb = 0, wb = 0, wb2 = 2;
    int k0 = 0;
    for (int i = 0; i < nsteps; ++i, k0 += BK) {
        const bool has1 = (i + 1) < nsteps;
        const bool has2 = (i + 2) < nsteps;
        if (has1) LOAD_X(k0 + BK);                 // x(i+1) -> regs
        if (has2) {
            STAGE_W(wb2, k0 + 2 * BK);             // W(i+2) -> LDS, stays in flight
            wb2 = (wb2 == 2) ? 0 : wb2 + 1;
        }
        COMPUTE(xb, wb);                           // ds_read + 48 MFMA
        wb = (wb == 2) ? 0 : wb + 1;
        if (has1) {
            CVT_X(xb ^ 1);                         // vmcnt(<=4) retires W(i+1)
            LGKM_BARRIER();                        // lgkm-only drain
            xb ^= 1;
        }
    }
    __syncthreads();               // full drain once before LDS reuse

    // ---- epilogue: LDS transpose -> coalesced float4 stores, 2 col-halves ----
    float* yt = (float*)smem;      // [128][132] fp32 = 67.6 KB
    const int erow = t >> 2;
    const int ec0  = (t & 3) * 4;
    #pragma unroll
    for (int h = 0; h < 2; ++h) {
        if ((wc >> 1) == h) {
            #pragma unroll
            for (int fr = 0; fr < 4; ++fr) {
                const int row0 = wr * 64 + fr * 16 + lq * 4;
                #pragma unroll
                for (int fc = 0; fc < 4; ++fc) {
                    const int col = (wc & 1) * 64 + fc * 16 + lr;
                    #pragma unroll
                    for (int i = 0; i < 4; ++i)
                        yt[(row0 + i) * 132 + col] = acc[fr][fc][i];
                }
            }
        }
        __syncthreads();
        #pragma unroll
        for (int j = 0; j < 8; ++j) {
            const int col = ec0 + j * 16;
            float4 v = *(const float4*)&yt[erow * 132 + col];
            const float4 bb = *(const float4*)&bias[n0 + h * 128 + col];
            v.x += bb.x; v.y += bb.y; v.z += bb.z; v.w += bb.w;
            *(float4*)&y[(size_t)(m0 + erow) * OUT_DIM + n0 + h * 128 + col] = v;
        }
        __syncthreads();
    }
}

// ---------------------------------------------------------------------------
extern "C" void kernel_launch(void* const* d_in, const int* in_sizes, int n_in,
                              void* d_out, int out_size, void* d_ws, size_t ws_size,
                              hipStream_t stream)
{
    const float* x    = (const float*)d_in[0];
    const float* W    = (const float*)d_in[1];
    const float* bias = (const float*)d_in[2];
    const float* wls  = (const float*)d_in[3];
    // d_in[4], d_in[5]: structural int masks (encoded in index math)

    unsigned short* wh = (unsigned short*)d_ws;                 // 2 MiB
    unsigned short* wl = wh + (size_t)OUT_DIM * IN_DIM;         // 2 MiB
    float* y   = (float*)d_out;                                 // [16384][1024]
    float* jac = y + (size_t)BATCH * OUT_DIM;                   // [128][8][8]

    prep_kernel<<<OUT_DIM / 4, 256, 0, stream>>>(W, wls, wh, wl, jac);

    gemm_kernel<<<4 * 128, 512, 0, stream>>>(x, wh, wl, bias, y);
}

// Round 7
// 191.918 us; speedup vs baseline: 1.0493x; 1.0493x over previous
//
#include <hip/hip_runtime.h>

#define IN_DIM   1024
#define OUT_DIM  1024
#define BATCH    16384

#define BM 128
#define BN 128
#define BK 32

typedef __attribute__((ext_vector_type(8))) short          bf16x8;
typedef __attribute__((ext_vector_type(8))) unsigned short u16x8;
typedef __attribute__((ext_vector_type(4))) unsigned short u16x4;
typedef __attribute__((ext_vector_type(4))) float          f32x4;

__device__ __forceinline__ unsigned short f2bf(float f) {
    unsigned u = __float_as_uint(f);
    u += 0x7FFFu + ((u >> 16) & 1u);          // round-to-nearest-even
    return (unsigned short)(u >> 16);
}
__device__ __forceinline__ float bf2f(unsigned short h) {
    return __uint_as_float((unsigned)h << 16);
}

#define GLOAD_LDS16(g, l)                                                      \
    __builtin_amdgcn_global_load_lds(                                          \
        (const __attribute__((address_space(1))) unsigned int*)(g),            \
        (__attribute__((address_space(3))) unsigned int*)(l), 16, 0, 0)

// ---------------------------------------------------------------------------
// Kernel 1: weight normalization -> split bf16 planes (wh + wl) + log-jac.
// One wave per row. Row o, block r=o>>3: cols [0,r*8) tril, [r*8,r*8+8) diag
// (exp), rest zero.
// ---------------------------------------------------------------------------
__global__ __launch_bounds__(256) void prep_kernel(
    const float* __restrict__ W, const float* __restrict__ wls,
    unsigned short* __restrict__ wh, unsigned short* __restrict__ wl,
    float* __restrict__ jac)
{
    const int warp = threadIdx.x >> 6;
    const int lane = threadIdx.x & 63;
    const int row  = blockIdx.x * 4 + warp;
    const int r    = row >> 3;
    const int d0   = r * 8;
    const int nk   = d0 + 8;
    const float* Wr = W + (size_t)row * IN_DIM;

    float ss = 0.f;
    for (int k = lane * 4; k < nk; k += 256) {
        float4 v = *(const float4*)&Wr[k];
        if (k >= d0) { v.x = expf(v.x); v.y = expf(v.y); v.z = expf(v.z); v.w = expf(v.w); }
        ss += v.x * v.x + v.y * v.y + v.z * v.z + v.w * v.w;
    }
    #pragma unroll
    for (int off = 32; off >= 1; off >>= 1) ss += __shfl_xor(ss, off);

    const float lscale = wls[row] - 0.5f * logf(ss);
    const float scale  = expf(lscale);

    for (int k = lane * 4; k < IN_DIM; k += 256) {
        float4 v = {0.f, 0.f, 0.f, 0.f};
        if (k < nk) {
            v = *(const float4*)&Wr[k];
            if (k >= d0) { v.x = expf(v.x); v.y = expf(v.y); v.z = expf(v.z); v.w = expf(v.w); }
            v.x *= scale; v.y *= scale; v.z *= scale; v.w *= scale;
        }
        u16x4 h, l;
        const float f[4] = {v.x, v.y, v.z, v.w};
        #pragma unroll
        for (int i = 0; i < 4; ++i) {
            h[i] = f2bf(f[i]);
            l[i] = f2bf(f[i] - bf2f(h[i]));
        }
        *(u16x4*)&wh[(size_t)row * IN_DIM + k] = h;
        *(u16x4*)&wl[(size_t)row * IN_DIM + k] = l;
    }
    if (lane < 8) jac[r * 64 + (row & 7) * 8 + lane] = lscale + Wr[d0 + lane];
}

// ---------------------------------------------------------------------------
// Kernel 2: y = x @ Wn^T + bias, bf16x2-split MFMA (hh + hl + lh).
// 128x128 tile, BK=32, 256 thr / 4 waves (2x2, 64x64 per wave), 64 KB LDS
// -> 2 blocks/CU: independent barrier groups hide each other's drains
// (m114 implicit overlap; no explicit waitcnt games after the R5 lesson).
// LDS is FRAGMENT-ORDERED: per plane, [row-block 16][kslot 0..3][row][8 bf16]
// so gload_lds dests, staging ds_writes and frag ds_reads are all lane-linear
// 1KB sub-tiles -> zero bank conflicts, no padding (rule #21 pattern).
// Plain __syncthreads 2-phase pipeline (R4 semantics, proven 86 us).
// ---------------------------------------------------------------------------
__global__ __launch_bounds__(256, 2) void gemm_kernel(
    const float* __restrict__ x,
    const unsigned short* __restrict__ wh, const unsigned short* __restrict__ wl,
    const float* __restrict__ bias, float* __restrict__ y)
{
    __shared__ __align__(16) unsigned short smem[32768];   // 64 KB
    // per buffer (16384 elems): xh[4096] | xl[4096] | wh[4096] | wl[4096]

    const int bid = (int)blockIdx.x;
    const int seg = bid >> 7;                  // 0..7, heaviest first
    const int sb  = bid & 127;
    const int nt  = 7 - seg;
    const int mt  = (sb & 7) * 16 + (sb >> 3); // XCD-affine: xcd owns 16 mts
    const int m0  = mt * BM;
    const int n0  = nt * BN;
    const int nsteps = (n0 + BN) >> 5;         // in {4,8,...,32}

    const int t    = threadIdx.x;
    const int lane = t & 63;
    const int wid  = t >> 6;
    const int wr   = wid >> 1;                 // 0..1
    const int wc   = wid & 1;                  // 0..1
    const int lr   = lane & 15;
    const int lq   = lane >> 4;

    // x staging: thread t owns fragment-slots t and t+256
    //   slot s: rb=s>>6, kslot=(s>>4)&3, row=s&15 -> 8 consecutive floats
    const int mA = ((t >> 6) & 3) * 16 + (t & 15);
    const int kA = ((t >> 4) & 3) * 8;
    const float* xg = x + (size_t)(m0 + mA) * IN_DIM + kA;

    // W staging: wave wid stages row-blocks {2wid, 2wid+1} of each plane
    const unsigned short* whg = wh + (size_t)(n0 + wid * 32 + lr) * IN_DIM + lq * 8;
    const unsigned short* wlg = wl + (size_t)(n0 + wid * 32 + lr) * IN_DIM + lq * 8;

    f32x4 acc[4][4];
    #pragma unroll
    for (int i = 0; i < 4; ++i)
        #pragma unroll
        for (int j = 0; j < 4; ++j) acc[i][j] = (f32x4){0.f, 0.f, 0.f, 0.f};

    float4 xva, xvb, xvc, xvd;

    auto LOAD_X = [&](int k0) {
        xva = *(const float4*)(xg + k0);
        xvb = *(const float4*)(xg + k0 + 4);
        xvc = *(const float4*)(xg + 64 * IN_DIM + k0);
        xvd = *(const float4*)(xg + 64 * IN_DIM + k0 + 4);
    };
    auto STAGE_W = [&](int b, int k0) {        // 4 gload_lds, lane-linear dests
        unsigned short* whp = smem + b * 16384 + 8192  + wid * 1024;
        unsigned short* wlp = smem + b * 16384 + 12288 + wid * 1024;
        GLOAD_LDS16(whg + k0,                whp);
        GLOAD_LDS16(whg + k0 + 16 * IN_DIM,  whp + 512);
        GLOAD_LDS16(wlg + k0,                wlp);
        GLOAD_LDS16(wlg + k0 + 16 * IN_DIM,  wlp + 512);
    };
    auto CVT_X = [&](int b) {                  // linear slot writes: t*8
        unsigned short* xhp = smem + b * 16384;
        unsigned short* xlp = xhp + 4096;
        const float fa[8] = {xva.x, xva.y, xva.z, xva.w, xvb.x, xvb.y, xvb.z, xvb.w};
        const float fb[8] = {xvc.x, xvc.y, xvc.z, xvc.w, xvd.x, xvd.y, xvd.z, xvd.w};
        u16x8 h0, l0, h1, l1;
        #pragma unroll
        for (int i = 0; i < 8; ++i) {
            h0[i] = f2bf(fa[i]);  l0[i] = f2bf(fa[i] - bf2f(h0[i]));
            h1[i] = f2bf(fb[i]);  l1[i] = f2bf(fb[i] - bf2f(h1[i]));
        }
        *(u16x8*)&xhp[t * 8]        = h0;
        *(u16x8*)&xlp[t * 8]        = l0;
        *(u16x8*)&xhp[2048 + t * 8] = h1;
        *(u16x8*)&xlp[2048 + t * 8] = l1;
    };
    auto COMPUTE = [&](int b) {
        const unsigned short* xh_ = smem + b * 16384;
        const unsigned short* xl_ = xh_ + 4096;
        const unsigned short* wh_ = xh_ + 8192;
        const unsigned short* wl_ = xh_ + 12288;
        const int ao = wr * 2048 + lane * 8;   // rb = wr*4+fr
        const int bo = wc * 2048 + lane * 8;   // rb = wc*4+fc
        bf16x8 bh[4], bl[4];
        #pragma unroll
        for (int fc = 0; fc < 4; ++fc) {
            bh[fc] = *(const bf16x8*)&wh_[bo + fc * 512];
            bl[fc] = *(const bf16x8*)&wl_[bo + fc * 512];
        }
        #pragma unroll
        for (int fr = 0; fr < 4; ++fr) {
            const bf16x8 ah = *(const bf16x8*)&xh_[ao + fr * 512];
            const bf16x8 al = *(const bf16x8*)&xl_[ao + fr * 512];
            #pragma unroll
            for (int fc = 0; fc < 4; ++fc) {
                acc[fr][fc] = __builtin_amdgcn_mfma_f32_16x16x32_bf16(ah, bh[fc], acc[fr][fc], 0, 0, 0);
                acc[fr][fc] = __builtin_amdgcn_mfma_f32_16x16x32_bf16(ah, bl[fc], acc[fr][fc], 0, 0, 0);
                acc[fr][fc] = __builtin_amdgcn_mfma_f32_16x16x32_bf16(al, bh[fc], acc[fr][fc], 0, 0, 0);
            }
        }
    };

    // prologue
    LOAD_X(0);
    STAGE_W(0, 0);
    CVT_X(0);
    __syncthreads();

    int buf = 0;
    int k0 = 0;
    for (int i = 0; i < nsteps; ++i, k0 += BK) {
        const bool has1 = (i + 1) < nsteps;
        if (has1) {
            LOAD_X(k0 + BK);
            STAGE_W(buf ^ 1, k0 + BK);
        }
        COMPUTE(buf);
        if (has1) CVT_X(buf ^ 1);
        __syncthreads();
        buf ^= 1;
    }

    // ---- epilogue: LDS transpose (two 64-row halves) -> coalesced stores ----
    float* yt = (float*)smem;                  // [64][132] fp32 = 33.8 KB
    const int er = t >> 2;                     // 0..63
    const int ec = (t & 3) * 4;
    #pragma unroll
    for (int h = 0; h < 2; ++h) {
        if (wr == h) {
            #pragma unroll
            for (int fr = 0; fr < 4; ++fr) {
                const int row0 = fr * 16 + lq * 4;
                #pragma unroll
                for (int fc = 0; fc < 4; ++fc) {
                    const int col = wc * 64 + fc * 16 + lr;
                    #pragma unroll
                    for (int i = 0; i < 4; ++i)
                        yt[(row0 + i) * 132 + col] = acc[fr][fc][i];
                }
            }
        }
        __syncthreads();
        #pragma unroll
        for (int j = 0; j < 8; ++j) {
            const int col = ec + j * 16;
            float4 v = *(const float4*)&yt[er * 132 + col];
            const float4 bb = *(const float4*)&bias[n0 + col];
            v.x += bb.x; v.y += bb.y; v.z += bb.z; v.w += bb.w;
            *(float4*)&y[(size_t)(m0 + h * 64 + er) * OUT_DIM + n0 + col] = v;
        }
        __syncthreads();
    }
}

// ---------------------------------------------------------------------------
extern "C" void kernel_launch(void* const* d_in, const int* in_sizes, int n_in,
                              void* d_out, int out_size, void* d_ws, size_t ws_size,
                              hipStream_t stream)
{
    const float* x    = (const float*)d_in[0];
    const float* W    = (const float*)d_in[1];
    const float* bias = (const float*)d_in[2];
    const float* wls  = (const float*)d_in[3];
    // d_in[4], d_in[5]: structural int masks (encoded in index math)

    unsigned short* wh = (unsigned short*)d_ws;                 // 2 MiB
    unsigned short* wl = wh + (size_t)OUT_DIM * IN_DIM;         // 2 MiB
    float* y   = (float*)d_out;                                 // [16384][1024]
    float* jac = y + (size_t)BATCH * OUT_DIM;                   // [128][8][8]

    prep_kernel<<<OUT_DIM / 4, 256, 0, stream>>>(W, wls, wh, wl, jac);

    gemm_kernel<<<8 * 128, 256, 0, stream>>>(x, wh, wl, bias, y);
}

// Round 11
// 180.088 us; speedup vs baseline: 1.1183x; 1.0657x over previous
//
#include <hip/hip_runtime.h>

#define IN_DIM   1024
#define OUT_DIM  1024
#define BATCH    16384

#define BM 128
#define BN 256
#define BK 32

typedef __attribute__((ext_vector_type(8))) _Float16       f16x8;
typedef __attribute__((ext_vector_type(4))) unsigned short u16x4;
typedef __attribute__((ext_vector_type(4))) float          f32x4;

__device__ __forceinline__ unsigned short f2h(float f) {
    _Float16 h = (_Float16)f;                 // RNE
    return __builtin_bit_cast(unsigned short, h);
}

#define GLOAD_LDS16(g, l)                                                      \
    __builtin_amdgcn_global_load_lds(                                          \
        (const __attribute__((address_space(1))) unsigned int*)(g),            \
        (__attribute__((address_space(3))) unsigned int*)(l), 16, 0, 0)

// ---------------------------------------------------------------------------
// Kernel 1: weight normalization -> single fp16 plane + exact log-jacobian.
// One wave per row. Row o, block r=o>>3: cols [0,r*8) tril, [r*8,r*8+8) diag
// (exp), rest zero.  jac stays exact fp32 (no fp16 involvement).
// ---------------------------------------------------------------------------
__global__ __launch_bounds__(256) void prep_kernel(
    const float* __restrict__ W, const float* __restrict__ wls,
    unsigned short* __restrict__ wf, float* __restrict__ jac)
{
    const int warp = threadIdx.x >> 6;
    const int lane = threadIdx.x & 63;
    const int row  = blockIdx.x * 4 + warp;
    const int r    = row >> 3;
    const int d0   = r * 8;
    const int nk   = d0 + 8;
    const float* Wr = W + (size_t)row * IN_DIM;

    float ss = 0.f;
    for (int k = lane * 4; k < nk; k += 256) {
        float4 v = *(const float4*)&Wr[k];
        if (k >= d0) { v.x = expf(v.x); v.y = expf(v.y); v.z = expf(v.z); v.w = expf(v.w); }
        ss += v.x * v.x + v.y * v.y + v.z * v.z + v.w * v.w;
    }
    #pragma unroll
    for (int off = 32; off >= 1; off >>= 1) ss += __shfl_xor(ss, off);

    const float lscale = wls[row] - 0.5f * logf(ss);
    const float scale  = expf(lscale);

    for (int k = lane * 4; k < IN_DIM; k += 256) {
        float4 v = {0.f, 0.f, 0.f, 0.f};
        if (k < nk) {
            v = *(const float4*)&Wr[k];
            if (k >= d0) { v.x = expf(v.x); v.y = expf(v.y); v.z = expf(v.z); v.w = expf(v.w); }
            v.x *= scale; v.y *= scale; v.z *= scale; v.w *= scale;
        }
        u16x4 h;
        h[0] = f2h(v.x); h[1] = f2h(v.y); h[2] = f2h(v.z); h[3] = f2h(v.w);
        *(u16x4*)&wf[(size_t)row * IN_DIM + k] = h;
    }
    if (lane < 8) jac[r * 64 + (row & 7) * 8 + lane] = lscale + Wr[d0 + lane];
}

// ---------------------------------------------------------------------------
// Kernel 2: y = x @ Wn^T + bias, SINGLE-PASS fp16 MFMA (16x16x32_f16).
// 128x256 tile, BK=32, 512 thr / 8 waves (2x4, 64x64 per wave).
// LDS: fragment-ordered, conflict-free, 24 KB/buffer -> 48 KB dbuf
// -> 2 blocks/CU (independent barrier groups hide each other's drains).
// W staged via global_load_lds (lane-linear dests); x reg-staged with fused
// fp32->fp16 conversion. Plain __syncthreads (R4-proven pipeline).
// ---------------------------------------------------------------------------
__global__ __launch_bounds__(512, 2) void gemm_kernel(
    const float* __restrict__ x, const unsigned short* __restrict__ wf,
    const float* __restrict__ bias, float* __restrict__ y)
{
    __shared__ __align__(16) unsigned short smem[24576];   // 48 KB
    // buffer b (12288 halves): x[4096] | w[8192], fragment-ordered:
    //   [row-block of 16][kslot 0..3][row 0..15][8 halves]

    const int bid = (int)blockIdx.x;
    const int seg = bid >> 7;                  // 0..3, heaviest first
    const int sb  = bid & 127;
    const int nt  = 3 - seg;
    const int mt  = (sb & 7) * 16 + (sb >> 3); // XCD-affine: xcd owns 16 mts
    const int m0  = mt * BM;
    const int n0  = nt * BN;
    const int nsteps = (n0 + BN) >> 5;         // (nt+1)*8 in {8,16,24,32}

    const int t    = threadIdx.x;
    const int lane = t & 63;
    const int wid  = t >> 6;
    const int wr   = wid >> 2;                 // 0..1 (row half)
    const int wc   = wid & 3;                  // 0..3 (col quarter)
    const int lr   = lane & 15;
    const int lq   = lane >> 4;

    // x staging: thread t owns fragment slot t (rb=t>>6, kslot=(t>>4)&3, row=t&15)
    const int mA = (t >> 6) * 16 + (t & 15);
    const int kA = ((t >> 4) & 3) * 8;
    const float* xg = x + (size_t)(m0 + mA) * IN_DIM + kA;

    // W staging: wave wid stages row-blocks {2wid, 2wid+1} (rows wid*32..+31)
    const unsigned short* wg = wf + (size_t)(n0 + wid * 32 + lr) * IN_DIM + lq * 8;

    f32x4 acc[4][4];
    #pragma unroll
    for (int i = 0; i < 4; ++i)
        #pragma unroll
        for (int j = 0; j < 4; ++j) acc[i][j] = (f32x4){0.f, 0.f, 0.f, 0.f};

    float4 xva, xvb;

    auto LOAD_X = [&](int k0) {
        xva = *(const float4*)(xg + k0);
        xvb = *(const float4*)(xg + k0 + 4);
    };
    auto STAGE_W = [&](int b, int k0) {        // 2 gload_lds, lane-linear dests
        unsigned short* wp = smem + b * 12288 + 4096 + wid * 1024;
        GLOAD_LDS16(wg + k0,               wp);        // rows wid*32..+15
        GLOAD_LDS16(wg + k0 + 16 * IN_DIM, wp + 512);  // rows +16..+31
    };
    auto CVT_X = [&](int b) {                  // linear slot write: t*8 halves
        unsigned short* xp = smem + b * 12288;
        const float f[8] = {xva.x, xva.y, xva.z, xva.w, xvb.x, xvb.y, xvb.z, xvb.w};
        f16x8 h;
        #pragma unroll
        for (int i = 0; i < 8; ++i) h[i] = (_Float16)f[i];
        *(f16x8*)&xp[t * 8] = h;
    };
    auto COMPUTE = [&](int b) {
        const unsigned short* xp = smem + b * 12288;
        const unsigned short* wp = xp + 4096;
        const int ao = wr * 2048 + lane * 8;   // A rb = wr*4+fr
        const int bo = wc * 2048 + lane * 8;   // B rb = wc*4+fc
        f16x8 bfr[4];
        #pragma unroll
        for (int fc = 0; fc < 4; ++fc)
            bfr[fc] = *(const f16x8*)&wp[bo + fc * 512];
        #pragma unroll
        for (int fr = 0; fr < 4; ++fr) {
            const f16x8 a = *(const f16x8*)&xp[ao + fr * 512];
            #pragma unroll
            for (int fc = 0; fc < 4; ++fc)
                acc[fr][fc] = __builtin_amdgcn_mfma_f32_16x16x32_f16(a, bfr[fc], acc[fr][fc], 0, 0, 0);
        }
    };

    // prologue
    LOAD_X(0);
    STAGE_W(0, 0);
    CVT_X(0);
    __syncthreads();

    int buf = 0;
    int k0 = 0;
    for (int i = 0; i < nsteps; ++i, k0 += BK) {
        const bool has1 = (i + 1) < nsteps;
        if (has1) {
            LOAD_X(k0 + BK);               // x(i+1) -> regs
            STAGE_W(buf ^ 1, k0 + BK);     // W(i+1) -> LDS, drains at barrier
        }
        COMPUTE(buf);
        if (has1) CVT_X(buf ^ 1);          // waits only the x loads
        __syncthreads();
        buf ^= 1;
    }

    // ---- epilogue: 4 quadrant passes through LDS -> fully coalesced stores ----
    float* yt = (float*)smem;              // [64][132] fp32 = 33.8 KB
    #pragma unroll
    for (int p = 0; p < 4; ++p) {
        const int h = p >> 1, c = p & 1;   // row half, col half
        if (wr == h && (wc >> 1) == c) {
            #pragma unroll
            for (int fr = 0; fr < 4; ++fr) {
                const int row0 = fr * 16 + lq * 4;
                #pragma unroll
                for (int fc = 0; fc < 4; ++fc) {
                    const int col = (wc & 1) * 64 + fc * 16 + lr;
                    #pragma unroll
                    for (int i = 0; i < 4; ++i)
                        yt[(row0 + i) * 132 + col] = acc[fr][fc][i];
                }
            }
        }
        __syncthreads();
        #pragma unroll
        for (int j = 0; j < 4; ++j) {      // 16 rows x 128 cols per pass
            const int r  = j * 16 + (t >> 5);
            const int c4 = (t & 31) * 4;
            float4 v = *(const float4*)&yt[r * 132 + c4];
            const float4 bb = *(const float4*)&bias[n0 + c * 128 + c4];
            v.x += bb.x; v.y += bb.y; v.z += bb.z; v.w += bb.w;
            *(float4*)&y[(size_t)(m0 + h * 64 + r) * OUT_DIM + n0 + c * 128 + c4] = v;
        }
        __syncthreads();
    }
}

// ---------------------------------------------------------------------------
extern "C" void kernel_launch(void* const* d_in, const int* in_sizes, int n_in,
                              void* d_out, int out_size, void* d_ws, size_t ws_size,
                              hipStream_t stream)
{
    const float* x    = (const float*)d_in[0];
    const float* W    = (const float*)d_in[1];
    const float* bias = (const float*)d_in[2];
    const float* wls  = (const float*)d_in[3];
    // d_in[4], d_in[5]: structural int masks (encoded in index math)

    unsigned short* wf = (unsigned short*)d_ws;      // fp16 Wn plane, 2 MiB
    float* y   = (float*)d_out;                      // [16384][1024]
    float* jac = y + (size_t)BATCH * OUT_DIM;        // [128][8][8]

    prep_kernel<<<OUT_DIM / 4, 256, 0, stream>>>(W, wls, wf, jac);

    gemm_kernel<<<4 * 128, 512, 0, stream>>>(x, wf, bias, y);
}

// Round 12
// 168.954 us; speedup vs baseline: 1.1919x; 1.0659x over previous
//
#include <hip/hip_runtime.h>

#define IN_DIM   1024
#define OUT_DIM  1024
#define BATCH    16384

#define BM 128
#define BN 256
#define BK 32

typedef __attribute__((ext_vector_type(8))) _Float16       f16x8;
typedef __attribute__((ext_vector_type(4))) unsigned short u16x4;
typedef __attribute__((ext_vector_type(4))) float          f32x4;

__device__ __forceinline__ unsigned short f2h(float f) {
    _Float16 h = (_Float16)f;                 // RNE
    return __builtin_bit_cast(unsigned short, h);
}

#define GLOAD_LDS16(g, l)                                                      \
    __builtin_amdgcn_global_load_lds(                                          \
        (const __attribute__((address_space(1))) unsigned int*)(g),            \
        (__attribute__((address_space(3))) unsigned int*)(l), 16, 0, 0)

// ---------------------------------------------------------------------------
// Kernel 1: weight normalization -> single fp16 plane + exact log-jacobian.
// ---------------------------------------------------------------------------
__global__ __launch_bounds__(256) void prep_kernel(
    const float* __restrict__ W, const float* __restrict__ wls,
    unsigned short* __restrict__ wf, float* __restrict__ jac)
{
    const int warp = threadIdx.x >> 6;
    const int lane = threadIdx.x & 63;
    const int row  = blockIdx.x * 4 + warp;
    const int r    = row >> 3;
    const int d0   = r * 8;
    const int nk   = d0 + 8;
    const float* Wr = W + (size_t)row * IN_DIM;

    float ss = 0.f;
    for (int k = lane * 4; k < nk; k += 256) {
        float4 v = *(const float4*)&Wr[k];
        if (k >= d0) { v.x = expf(v.x); v.y = expf(v.y); v.z = expf(v.z); v.w = expf(v.w); }
        ss += v.x * v.x + v.y * v.y + v.z * v.z + v.w * v.w;
    }
    #pragma unroll
    for (int off = 32; off >= 1; off >>= 1) ss += __shfl_xor(ss, off);

    const float lscale = wls[row] - 0.5f * logf(ss);
    const float scale  = expf(lscale);

    for (int k = lane * 4; k < IN_DIM; k += 256) {
        float4 v = {0.f, 0.f, 0.f, 0.f};
        if (k < nk) {
            v = *(const float4*)&Wr[k];
            if (k >= d0) { v.x = expf(v.x); v.y = expf(v.y); v.z = expf(v.z); v.w = expf(v.w); }
            v.x *= scale; v.y *= scale; v.z *= scale; v.w *= scale;
        }
        u16x4 h;
        h[0] = f2h(v.x); h[1] = f2h(v.y); h[2] = f2h(v.z); h[3] = f2h(v.w);
        *(u16x4*)&wf[(size_t)row * IN_DIM + k] = h;
    }
    if (lane < 8) jac[r * 64 + (row & 7) * 8 + lane] = lscale + Wr[d0 + lane];
}

// ---------------------------------------------------------------------------
// Kernel 2: y = x @ Wn^T + bias, single-pass fp16 MFMA (16x16x32_f16).
// 128x256 tile, BK=32, 512 thr / 8 waves (2x4, 64x64 per wave).
// LDS fragment-ordered conflict-free, 24 KB/buffer, dbuf 48 KB.
// x prefetched TWO K-steps ahead into regs (parity via manual 2x unroll, no
// runtime-indexed reg arrays) so CVT consumes loads issued a full iteration
// earlier -> x L3 latency fully hidden. W gload_lds issued before COMPUTE
// (L2-hot panel, hidden under compute). Plain __syncthreads per K-step.
// ---------------------------------------------------------------------------
__global__ __launch_bounds__(512, 2) void gemm_kernel(
    const float* __restrict__ x, const unsigned short* __restrict__ wf,
    const float* __restrict__ bias, float* __restrict__ y)
{
    __shared__ __align__(16) unsigned short smem[24576];   // 48 KB
    // buffer b (12288 halves): x[4096] | w[8192], fragment-ordered:
    //   [row-block of 16][kslot 0..3][row 0..15][8 halves]

    const int bid = (int)blockIdx.x;
    const int seg = bid >> 7;                  // 0..3, heaviest first
    const int sb  = bid & 127;
    const int nt  = 3 - seg;
    const int mt  = (sb & 7) * 16 + (sb >> 3); // XCD-affine: xcd owns 16 mts
    const int m0  = mt * BM;
    const int n0  = nt * BN;
    const int Klim   = n0 + BN;
    const int nsteps = Klim >> 5;              // (nt+1)*8 in {8,16,24,32}, even

    const int t    = threadIdx.x;
    const int lane = t & 63;
    const int wid  = t >> 6;
    const int wr   = wid >> 2;                 // 0..1 (row half)
    const int wc   = wid & 3;                  // 0..3 (col quarter)
    const int lr   = lane & 15;
    const int lq   = lane >> 4;

    // x staging: thread t owns fragment slot t (rb=t>>6, kslot=(t>>4)&3, row=t&15)
    const int mA = (t >> 6) * 16 + (t & 15);
    const int kA = ((t >> 4) & 3) * 8;
    const float* xg = x + (size_t)(m0 + mA) * IN_DIM + kA;

    // W staging: wave wid stages row-blocks {2wid, 2wid+1} (rows wid*32..+31)
    const unsigned short* wg = wf + (size_t)(n0 + wid * 32 + lr) * IN_DIM + lq * 8;

    f32x4 acc[4][4];
    #pragma unroll
    for (int i = 0; i < 4; ++i)
        #pragma unroll
        for (int j = 0; j < 4; ++j) acc[i][j] = (f32x4){0.f, 0.f, 0.f, 0.f};

    float4 xA0, xA1, xB0, xB1;                 // two x reg sets (A/B parity)

    auto STAGE_W = [&](int b, int k0) {        // 2 gload_lds, lane-linear dests
        unsigned short* wp = smem + b * 12288 + 4096 + wid * 1024;
        GLOAD_LDS16(wg + k0,               wp);        // rows wid*32..+15
        GLOAD_LDS16(wg + k0 + 16 * IN_DIM, wp + 512);  // rows +16..+31
    };
    auto CVT = [&](int b, const float4& v0, const float4& v1) {
        unsigned short* xp = smem + b * 12288;
        const float f[8] = {v0.x, v0.y, v0.z, v0.w, v1.x, v1.y, v1.z, v1.w};
        f16x8 h;
        #pragma unroll
        for (int i = 0; i < 8; ++i) h[i] = (_Float16)f[i];
        *(f16x8*)&xp[t * 8] = h;
    };
    auto COMPUTE = [&](int b) {
        const unsigned short* xp = smem + b * 12288;
        const unsigned short* wp = xp + 4096;
        const int ao = wr * 2048 + lane * 8;   // A rb = wr*4+fr
        const int bo = wc * 2048 + lane * 8;   // B rb = wc*4+fc
        f16x8 bfr[4];
        #pragma unroll
        for (int fc = 0; fc < 4; ++fc)
            bfr[fc] = *(const f16x8*)&wp[bo + fc * 512];
        #pragma unroll
        for (int fr = 0; fr < 4; ++fr) {
            const f16x8 a = *(const f16x8*)&xp[ao + fr * 512];
            #pragma unroll
            for (int fc = 0; fc < 4; ++fc)
                acc[fr][fc] = __builtin_amdgcn_mfma_f32_16x16x32_f16(a, bfr[fc], acc[fr][fc], 0, 0, 0);
        }
    };

    // ---- prologue: buf0 = step0; regs B = x(1) ----
    xA0 = *(const float4*)(xg);  xA1 = *(const float4*)(xg + 4);   // x(0)
    STAGE_W(0, 0);
    CVT(0, xA0, xA1);
    xB0 = *(const float4*)(xg + BK);  xB1 = *(const float4*)(xg + BK + 4);  // x(1)
    __syncthreads();

    // ---- main loop, 2x unrolled for static reg parity ----
    // iter i (buf=i&1): STAGE_W(i+1); prefetch x(i+2) into free set;
    // COMPUTE(i); CVT(i+1) from the set loaded at iter i-1.
    for (int i = 0; i < nsteps; i += 2) {
        {   // even sub-iter: consume B (x(i+1)), prefetch A (x(i+2))
            const int k0 = i << 5;
            const bool has1 = (i + 1) < nsteps;
            if (has1) STAGE_W(1, k0 + BK);
            const int kp = (k0 + 2 * BK < Klim) ? (k0 + 2 * BK) : 0;
            xA0 = *(const float4*)(xg + kp);  xA1 = *(const float4*)(xg + kp + 4);
            COMPUTE(0);
            if (has1) CVT(1, xB0, xB1);
            __syncthreads();
        }
        {   // odd sub-iter: consume A (x(i+2)), prefetch B (x(i+3))
            const int i1 = i + 1;
            const int k0 = i1 << 5;
            const bool has1 = (i1 + 1) < nsteps;
            if (i1 < nsteps) {
                if (has1) STAGE_W(0, k0 + BK);
                const int kp = (k0 + 2 * BK < Klim) ? (k0 + 2 * BK) : 0;
                xB0 = *(const float4*)(xg + kp);  xB1 = *(const float4*)(xg + kp + 4);
                COMPUTE(1);
                if (has1) CVT(0, xA0, xA1);
                __syncthreads();
            }
        }
    }

    // ---- epilogue: 4 quadrant passes through LDS -> fully coalesced stores ----
    float* yt = (float*)smem;              // [64][132] fp32 = 33.8 KB
    #pragma unroll
    for (int p = 0; p < 4; ++p) {
        const int h = p >> 1, c = p & 1;   // row half, col half
        if (wr == h && (wc >> 1) == c) {
            #pragma unroll
            for (int fr = 0; fr < 4; ++fr) {
                const int row0 = fr * 16 + lq * 4;
                #pragma unroll
                for (int fc = 0; fc < 4; ++fc) {
                    const int col = (wc & 1) * 64 + fc * 16 + lr;
                    #pragma unroll
                    for (int i = 0; i < 4; ++i)
                        yt[(row0 + i) * 132 + col] = acc[fr][fc][i];
                }
            }
        }
        __syncthreads();
        #pragma unroll
        for (int j = 0; j < 4; ++j) {      // 16 rows x 128 cols per pass
            const int r  = j * 16 + (t >> 5);
            const int c4 = (t & 31) * 4;
            float4 v = *(const float4*)&yt[r * 132 + c4];
            const float4 bb = *(const float4*)&bias[n0 + c * 128 + c4];
            v.x += bb.x; v.y += bb.y; v.z += bb.z; v.w += bb.w;
            *(float4*)&y[(size_t)(m0 + h * 64 + r) * OUT_DIM + n0 + c * 128 + c4] = v;
        }
        __syncthreads();
    }
}

// ---------------------------------------------------------------------------
extern "C" void kernel_launch(void* const* d_in, const int* in_sizes, int n_in,
                              void* d_out, int out_size, void* d_ws, size_t ws_size,
                              hipStream_t stream)
{
    const float* x    = (const float*)d_in[0];
    const float* W    = (const float*)d_in[1];
    const float* bias = (const float*)d_in[2];
    const float* wls  = (const float*)d_in[3];
    // d_in[4], d_in[5]: structural int masks (encoded in index math)

    unsigned short* wf = (unsigned short*)d_ws;      // fp16 Wn plane, 2 MiB
    float* y   = (float*)d_out;                      // [16384][1024]
    float* jac = y + (size_t)BATCH * OUT_DIM;        // [128][8][8]

    prep_kernel<<<OUT_DIM / 4, 256, 0, stream>>>(W, wls, wf, jac);

    gemm_kernel<<<4 * 128, 512, 0, stream>>>(x, wf, bias, y);
}